// Round 12
// baseline (263.452 us; speedup 1.0000x reference)
//
#include <hip/hip_runtime.h>
#include <hip/hip_bf16.h>
#include <math.h>

typedef __attribute__((ext_vector_type(8))) short bf16x8;
typedef __attribute__((ext_vector_type(4))) float f32x4;

__device__ __forceinline__ float sigmoidf_(float x){ return 1.f/(1.f + expf(-x)); }
__device__ __forceinline__ short f2bf(float x){
    union { __hip_bfloat16 h; short s; } u; u.h = __float2bfloat16(x); return u.s;
}
__device__ __forceinline__ float bf2f(short s){
    union { unsigned u; float f; } v; v.u = ((unsigned)(unsigned short)s) << 16; return v.f;
}

// =====================================================================================
// bf16 MFMA GEMM core (R5 structure: direct loads, compiler-scheduled).
// TRANS=1: W is [N][K] row-major; TRANS=0: W is [K][N] row-major.
// =====================================================================================
template<int TRANS, int BIAS>
__device__ __forceinline__ void mm_core(
    const short* __restrict__ Abf, const float* __restrict__ W,
    const float* __restrict__ bias, float* __restrict__ outP,
    int K, int Kp, int N, int ks0, int ks1, int nblk)
{
    const int lane = threadIdx.x & 63;
    const int wave = threadIdx.x >> 6;
    const int l16  = lane & 15;
    const int lg   = lane >> 4;
    const int n    = nblk*64 + wave*16 + l16;
    const int nc   = min(n, N-1);

    f32x4 acc[4];
#pragma unroll
    for (int mt = 0; mt < 4; mt++) acc[mt] = f32x4{0.f,0.f,0.f,0.f};

    for (int ks = ks0; ks < ks1; ks++) {
        const int kl = ks*32 + lg*8;
        const short* ap = Abf + (long)l16*Kp + kl;
        bf16x8 a0 = *(const bf16x8*)(ap);
        bf16x8 a1 = *(const bf16x8*)(ap + (long)16*Kp);
        bf16x8 a2 = *(const bf16x8*)(ap + (long)32*Kp);
        bf16x8 a3 = *(const bf16x8*)(ap + (long)48*Kp);
        float wv[8];
        if (TRANS) {
            const float* wr = W + (long)nc*K;
            if (kl + 8 <= K) {
                float4 f0 = *(const float4*)(wr + kl);
                float4 f1 = *(const float4*)(wr + kl + 4);
                wv[0]=f0.x; wv[1]=f0.y; wv[2]=f0.z; wv[3]=f0.w;
                wv[4]=f1.x; wv[5]=f1.y; wv[6]=f1.z; wv[7]=f1.w;
            } else {
#pragma unroll
                for (int j=0;j<8;j++) wv[j] = wr[min(kl+j, K-1)];
            }
        } else {
            const float* wk = W + (long)kl*(long)N + nc;
            if (kl + 8 <= K) {
#pragma unroll
                for (int j=0;j<8;j++) wv[j] = wk[(long)j*N];
            } else {
#pragma unroll
                for (int j=0;j<8;j++) wv[j] = (kl+j < K) ? wk[(long)j*N] : 0.f;
            }
        }
        bf16x8 b;
#pragma unroll
        for (int j=0;j<8;j++) b[j] = f2bf(wv[j]);

        acc[0] = __builtin_amdgcn_mfma_f32_16x16x32_bf16(a0, b, acc[0], 0, 0, 0);
        acc[1] = __builtin_amdgcn_mfma_f32_16x16x32_bf16(a1, b, acc[1], 0, 0, 0);
        acc[2] = __builtin_amdgcn_mfma_f32_16x16x32_bf16(a2, b, acc[2], 0, 0, 0);
        acc[3] = __builtin_amdgcn_mfma_f32_16x16x32_bf16(a3, b, acc[3], 0, 0, 0);
    }

    if (n < N) {
        const float bv = BIAS ? bias[n] : 0.f;
#pragma unroll
        for (int mt = 0; mt < 4; mt++) {
#pragma unroll
            for (int q = 0; q < 4; q++) {
                int row = mt*16 + lg*4 + q;
                outP[(long)row*N + n] = acc[mt][q] + bv;
            }
        }
    }
}

// =====================================================================================
// Split-precision (hi+lo bf16, 4 products) core — fp32-class accuracy (pt path).
// =====================================================================================
template<int TRANS>
__device__ __forceinline__ void mm_core4(
    const short* __restrict__ Ahi, const short* __restrict__ Alo,
    const float* __restrict__ W, float* __restrict__ outP,
    int K, int Kp, int N, int ks0, int ks1, int nblk)
{
    const int lane = threadIdx.x & 63;
    const int wave = threadIdx.x >> 6;
    const int l16  = lane & 15;
    const int lg   = lane >> 4;
    const int n    = nblk*64 + wave*16 + l16;
    const int nc   = min(n, N-1);

    f32x4 acc[4];
#pragma unroll
    for (int mt = 0; mt < 4; mt++) acc[mt] = f32x4{0.f,0.f,0.f,0.f};

    for (int ks = ks0; ks < ks1; ks++) {
        const int kl = ks*32 + lg*8;
        const long o0 = (long)l16*Kp + kl;
        bf16x8 ah0 = *(const bf16x8*)(Ahi + o0);
        bf16x8 ah1 = *(const bf16x8*)(Ahi + o0 + (long)16*Kp);
        bf16x8 ah2 = *(const bf16x8*)(Ahi + o0 + (long)32*Kp);
        bf16x8 ah3 = *(const bf16x8*)(Ahi + o0 + (long)48*Kp);
        bf16x8 al0 = *(const bf16x8*)(Alo + o0);
        bf16x8 al1 = *(const bf16x8*)(Alo + o0 + (long)16*Kp);
        bf16x8 al2 = *(const bf16x8*)(Alo + o0 + (long)32*Kp);
        bf16x8 al3 = *(const bf16x8*)(Alo + o0 + (long)48*Kp);
        float wv[8];
        if (TRANS) {
            const float* wr = W + (long)nc*K;
            if (kl + 8 <= K) {
                float4 f0 = *(const float4*)(wr + kl);
                float4 f1 = *(const float4*)(wr + kl + 4);
                wv[0]=f0.x; wv[1]=f0.y; wv[2]=f0.z; wv[3]=f0.w;
                wv[4]=f1.x; wv[5]=f1.y; wv[6]=f1.z; wv[7]=f1.w;
            } else {
#pragma unroll
                for (int j=0;j<8;j++) wv[j] = wr[min(kl+j, K-1)];
            }
        } else {
            const float* wk = W + (long)kl*(long)N + nc;
            if (kl + 8 <= K) {
#pragma unroll
                for (int j=0;j<8;j++) wv[j] = wk[(long)j*N];
            } else {
#pragma unroll
                for (int j=0;j<8;j++) wv[j] = (kl+j < K) ? wk[(long)j*N] : 0.f;
            }
        }
        bf16x8 bh, bl;
#pragma unroll
        for (int j=0;j<8;j++) {
            short h = f2bf(wv[j]);
            bh[j] = h;
            bl[j] = f2bf(wv[j] - bf2f(h));
        }
        acc[0] = __builtin_amdgcn_mfma_f32_16x16x32_bf16(ah0, bh, acc[0], 0, 0, 0);
        acc[1] = __builtin_amdgcn_mfma_f32_16x16x32_bf16(ah1, bh, acc[1], 0, 0, 0);
        acc[2] = __builtin_amdgcn_mfma_f32_16x16x32_bf16(ah2, bh, acc[2], 0, 0, 0);
        acc[3] = __builtin_amdgcn_mfma_f32_16x16x32_bf16(ah3, bh, acc[3], 0, 0, 0);
        acc[0] = __builtin_amdgcn_mfma_f32_16x16x32_bf16(ah0, bl, acc[0], 0, 0, 0);
        acc[1] = __builtin_amdgcn_mfma_f32_16x16x32_bf16(ah1, bl, acc[1], 0, 0, 0);
        acc[2] = __builtin_amdgcn_mfma_f32_16x16x32_bf16(ah2, bl, acc[2], 0, 0, 0);
        acc[3] = __builtin_amdgcn_mfma_f32_16x16x32_bf16(ah3, bl, acc[3], 0, 0, 0);
        acc[0] = __builtin_amdgcn_mfma_f32_16x16x32_bf16(al0, bh, acc[0], 0, 0, 0);
        acc[1] = __builtin_amdgcn_mfma_f32_16x16x32_bf16(al1, bh, acc[1], 0, 0, 0);
        acc[2] = __builtin_amdgcn_mfma_f32_16x16x32_bf16(al2, bh, acc[2], 0, 0, 0);
        acc[3] = __builtin_amdgcn_mfma_f32_16x16x32_bf16(al3, bh, acc[3], 0, 0, 0);
        acc[0] = __builtin_amdgcn_mfma_f32_16x16x32_bf16(al0, bl, acc[0], 0, 0, 0);
        acc[1] = __builtin_amdgcn_mfma_f32_16x16x32_bf16(al1, bl, acc[1], 0, 0, 0);
        acc[2] = __builtin_amdgcn_mfma_f32_16x16x32_bf16(al2, bl, acc[2], 0, 0, 0);
        acc[3] = __builtin_amdgcn_mfma_f32_16x16x32_bf16(al3, bl, acc[3], 0, 0, 0);
    }

    if (n < N) {
#pragma unroll
        for (int mt = 0; mt < 4; mt++) {
#pragma unroll
            for (int q = 0; q < 4; q++) {
                int row = mt*16 + lg*4 + q;
                outP[(long)row*N + n] = acc[mt][q];
            }
        }
    }
}

// ============ prep: hi/lo A matrices, zero tails =====================================
__global__ void k_prep(const int* __restrict__ dec_in, const float* __restrict__ attn_h,
                       const float* __restrict__ embed, const float* __restrict__ h0,
                       short* __restrict__ xhi, short* __restrict__ xlo,
                       short* __restrict__ h0hi, short* __restrict__ h0lo,
                       short* __restrict__ x1hi, short* __restrict__ x1lo,
                       short* __restrict__ hthi, short* __restrict__ htlo,
                       short* __restrict__ habf, short* __restrict__ catbf)
{
    int i = blockIdx.x*256 + threadIdx.x;
    if (i < 64*1312) {                       // x [64][1312]
        int b = i / 1312, k = i % 1312;
        float v = 0.f;
        if (k < 300)       v = embed[(long)dec_in[b]*300 + k];
        else if (k < 1300) v = attn_h[b*1000 + (k-300)];
        short h = f2bf(v);
        xhi[i] = h; xlo[i] = f2bf(v - bf2f(h));
        return;
    }
    i -= 64*1312;
    if (i < 4*64*512) {                      // h0 [4][64][512]
        int d = i >> 15, r = i & 32767, b = r >> 9, k = r & 511;
        float v = (k < 500) ? h0[((long)d*64 + b)*500 + k] : 0.f;
        short h = f2bf(v);
        h0hi[i] = h; h0lo[i] = f2bf(v - bf2f(h));
        return;
    }
    i -= 4*64*512;
    if (i < 1536) {                          // x1/ht hi+lo tails
        int b = i/24; long o = (long)b*1024 + 1000 + i%24;
        x1hi[o]=0; x1lo[o]=0; hthi[o]=0; htlo[o]=0; return;
    }
    i -= 1536;
    if (i < 1536) { int b = i/24; habf[(long)b*1024 + 1000 + i%24] = 0; return; }
    i -= 1536;
    if (i < 3072) { int b = i/48; catbf[(long)b*2048 + 2000 + i%48] = 0; return; }
}

// ============ GRU GEMMs not needing x1: z 0,1=L0ih; 2,3=L0hh; 4,5=L1hh ===============
__global__ __launch_bounds__(256) void k_gru_mm0(
    const short* __restrict__ xhi, const short* __restrict__ xlo,
    const short* __restrict__ h0hi, const short* __restrict__ h0lo,
    const float* __restrict__ w_ih0, const float* __restrict__ w_hh0,
    const float* __restrict__ w_hh1,
    float* __restrict__ PgiL0, float* __restrict__ PghL0, float* __restrict__ PghL1)
{
    int z = blockIdx.z, s = blockIdx.y, nblk = blockIdx.x;
    if (z < 2) {                              // L0 ih: K=1300 Kp=1312, 41 ksteps, S=5x9
        mm_core4<1>(xhi, xlo, w_ih0 + (long)z*1500*1300,
                    PgiL0 + (long)(z*5 + s)*96000, 1300, 1312, 1500,
                    s*9, min(41, s*9+9), nblk);
    } else {
        if (s >= 2) return;                   // hh: K=500 Kp=512, 16 ksteps, S=2x8
        int d = (z < 4) ? (z - 2) : (z - 4);
        const float* W = ((z < 4) ? w_hh0 : w_hh1) + (long)d*750000;
        float* outP = ((z < 4) ? PghL0 : PghL1) + (long)(d*2 + s)*96000;
        const long ao = (long)(((z < 4) ? 0 : 2) + d)*32768;
        mm_core4<1>(h0hi + ao, h0lo + ao, W, outP, 500, 512, 1500, s*8, s*8+8, nblk);
    }
}

// ============ L1 ih GEMM (needs x1): z 0,1 = dirs; S=4x8 =============================
__global__ __launch_bounds__(256) void k_gru_ih1(
    const short* __restrict__ x1hi, const short* __restrict__ x1lo,
    const float* __restrict__ w_ih1, float* __restrict__ PgiL1)
{
    int z = blockIdx.z, s = blockIdx.y, nblk = blockIdx.x;
    mm_core4<1>(x1hi, x1lo, w_ih1 + (long)z*1500*1000,
                PgiL1 + (long)(z*4 + s)*96000, 1000, 1024, 1500,
                s*8, min(32, s*8+8), nblk);
}

// ============ NN split-K GEMM, split-precision (Wp) ==================================
__global__ __launch_bounds__(256) void k_nn_split4(
    const short* __restrict__ Ahi, const short* __restrict__ Alo,
    const float* __restrict__ W,
    float* __restrict__ P, int K, int Kp, int N, int steps)
{
    int s = blockIdx.y;
    int ks0 = s*steps, ks1 = min(Kp >> 5, ks0 + steps);
    if (ks0 >= ks1) return;
    mm_core4<0>(Ahi, Alo, W, P + (long)s*64*N, K, Kp, N, ks0, ks1, blockIdx.x);
}

// ============ Wc GEMM, full-K single kernel, fused bias+tanh+bf16 epilogue ===========
__global__ __launch_bounds__(256) void k_wc_full(
    const short* __restrict__ catbf, const float* __restrict__ W,
    const float* __restrict__ bias, short* __restrict__ habf)
{
    const int N = 1000, K = 2000, Kp = 2048;
    const int lane = threadIdx.x & 63;
    const int wave = threadIdx.x >> 6;
    const int l16  = lane & 15;
    const int lg   = lane >> 4;
    const int n    = blockIdx.x*64 + wave*16 + l16;
    const int nc   = min(n, N-1);

    f32x4 acc[4];
#pragma unroll
    for (int mt = 0; mt < 4; mt++) acc[mt] = f32x4{0.f,0.f,0.f,0.f};

    for (int ks = 0; ks < 64; ks++) {
        const int kl = ks*32 + lg*8;
        const short* ap = catbf + (long)l16*Kp + kl;
        bf16x8 a0 = *(const bf16x8*)(ap);
        bf16x8 a1 = *(const bf16x8*)(ap + (long)16*Kp);
        bf16x8 a2 = *(const bf16x8*)(ap + (long)32*Kp);
        bf16x8 a3 = *(const bf16x8*)(ap + (long)48*Kp);
        float wv[8];
        const float* wk = W + (long)kl*(long)N + nc;
        if (kl + 8 <= K) {
#pragma unroll
            for (int j=0;j<8;j++) wv[j] = wk[(long)j*N];
        } else {
#pragma unroll
            for (int j=0;j<8;j++) wv[j] = (kl+j < K) ? wk[(long)j*N] : 0.f;
        }
        bf16x8 b;
#pragma unroll
        for (int j=0;j<8;j++) b[j] = f2bf(wv[j]);
        acc[0] = __builtin_amdgcn_mfma_f32_16x16x32_bf16(a0, b, acc[0], 0, 0, 0);
        acc[1] = __builtin_amdgcn_mfma_f32_16x16x32_bf16(a1, b, acc[1], 0, 0, 0);
        acc[2] = __builtin_amdgcn_mfma_f32_16x16x32_bf16(a2, b, acc[2], 0, 0, 0);
        acc[3] = __builtin_amdgcn_mfma_f32_16x16x32_bf16(a3, b, acc[3], 0, 0, 0);
    }

    if (n < N) {
        const float bv = bias[n];
#pragma unroll
        for (int mt = 0; mt < 4; mt++) {
#pragma unroll
            for (int q = 0; q < 4; q++) {
                int row = mt*16 + lg*4 + q;          // = batch b
                habf[(long)row*1024 + n] = f2bf(tanhf(acc[mt][q] + bv));
            }
        }
    }
}

// ============ output projection (single precision, bias) =============================
__global__ __launch_bounds__(256) void k_out_mm(
    const short* __restrict__ Abf, const float* __restrict__ W,
    const float* __restrict__ bias, float* __restrict__ y)
{
    mm_core<0,1>(Abf, W, bias, y, 1000, 1024, 50257, 0, 32, blockIdx.x);
}

// ============ GRU gates: sum split-K partials + biases ===============================
template<int LAYER>
__global__ void k_gates(const float* __restrict__ Pgi, const float* __restrict__ Pgh,
                        const float* __restrict__ h0,
                        const float* __restrict__ b_ih, const float* __restrict__ b_hh,
                        short* __restrict__ outhi, short* __restrict__ outlo,
                        float* __restrict__ ht, int SI, int SH)
{
    const int d = blockIdx.y;
    int i = blockIdx.x*256 + threadIdx.x;
    if (i >= 32000) return;
    int b = i / 500, q = i % 500;
    long base = (long)b*1500 + q;
    float g0 = b_ih[d*1500 + q], g1 = b_ih[d*1500 + 500 + q], g2 = b_ih[d*1500 + 1000 + q];
    for (int s = 0; s < SI; s++) {
        const float* P = Pgi + (long)(d*SI + s)*96000 + base;
        g0 += P[0]; g1 += P[500]; g2 += P[1000];
    }
    float h0v = b_hh[d*1500 + q], h1v = b_hh[d*1500 + 500 + q], h2v = b_hh[d*1500 + 1000 + q];
    for (int s = 0; s < SH; s++) {
        const float* P = Pgh + (long)(d*SH + s)*96000 + base;
        h0v += P[0]; h1v += P[500]; h2v += P[1000];
    }
    float hp = h0[((long)(LAYER*2 + d)*64 + b)*500 + q];
    float r = sigmoidf_(g0 + h0v);
    float z = sigmoidf_(g1 + h1v);
    float nn = tanhf(g2 + r*h2v);
    float o = (1.f - z)*nn + z*hp;
    long oo = (long)b*1024 + d*500 + q;
    short h = f2bf(o);
    outhi[oo] = h; outlo[oo] = f2bf(o - bf2f(h));
    if (LAYER == 1) ht[(long)b*1000 + d*500 + q] = o;
}

// ============ windowed attention with fused pt; writes catbf [64][2048] bf16 ==========
__global__ void k_attn(const float* __restrict__ enc, const float* __restrict__ ht,
                       const float* __restrict__ Pwp, const float* __restrict__ Wp_b,
                       const float* __restrict__ Vp_w, const float* __restrict__ Vp_b,
                       const int* __restrict__ lengths, short* __restrict__ catbf)
{
    int b = blockIdx.x;
    __shared__ float hts[1000];
    __shared__ float hs[11][1000];
    __shared__ float aa[16];
    __shared__ float red[4];
    __shared__ int sp[2];
    int tid = threadIdx.x;
    int lane = tid & 63, wave = tid >> 6;

    // ---- fused pt: sum Wp partials, tanh, dot with Vp ----
    float ps = 0.f;
    for (int j = tid; j < 1000; j += 256) {
        float v = Wp_b[j];
#pragma unroll
        for (int s = 0; s < 8; s++) v += Pwp[(long)s*64000 + (long)b*1000 + j];
        ps += tanhf(v) * Vp_w[j];
    }
    for (int off = 32; off; off >>= 1) ps += __shfl_down(ps, off);
    if (lane == 0) red[wave] = ps;
    // float4-vectorized ht staging (1000 = 250 x float4)
    if (tid < 250) ((float4*)hts)[tid] = ((const float4*)(ht + (long)b*1000))[tid];
    __syncthreads();
    if (tid == 0) {
        float tot = red[0] + red[1] + red[2] + red[3];
        float s = 1.f/(1.f + expf(-(tot + Vp_b[0])));
        int len = lengths[b];
        int pt = (int)((float)len * s);
        sp[0] = min(len - 5, max(0, pt - 5));
        sp[1] = min(len, pt + 6);
    }
    __syncthreads();
    int p0 = sp[0], p1 = sp[1];

    for (int k = 0; k < 11; k++) {
        int row = min(p0 + k, 1023);
        const float4* er = (const float4*)(enc + ((long)b*1024 + row)*1000);
        if (tid < 250) ((float4*)hs[k])[tid] = er[tid];
    }
    __syncthreads();
    for (int k = wave; k < 11; k += 4) {
        float d = 0.f;
        for (int h = lane; h < 1000; h += 64) d += hts[h]*hs[k][h];
        for (int off = 32; off; off >>= 1) d += __shfl_down(d, off);
        if (lane == 0) aa[k] = d;
    }
    __syncthreads();
    if (tid == 0) {
        int nv = min(p1 - p0, 11);
        float m = -1e30f;
        for (int k = 0; k < nv; k++) m = fmaxf(m, aa[k]);
        float ssum = 0.f;
        for (int k = 0; k < 11; k++) { float e = (k < nv) ? expf(aa[k]-m) : 0.f; aa[k] = e; ssum += e; }
        float inv = 1.f/ssum;
        for (int k = 0; k < 11; k++) aa[k] *= inv;
    }
    __syncthreads();
    for (int h = tid; h < 1000; h += 256) {
        float c = 0.f;
#pragma unroll
        for (int k = 0; k < 11; k++) c += aa[k]*hs[k][h];
        catbf[(long)b*2048 + h]        = f2bf(c);
        catbf[(long)b*2048 + 1000 + h] = f2bf(hts[h]);
    }
}

// ============ log_softmax partials (online m,s per 1/8 row slice) ====================
__global__ void k_lse_part(const float* __restrict__ y, float* __restrict__ part)
{
    const int V = 50257;
    int b = blockIdx.x >> 3, p = blockIdx.x & 7;
    const int Vc = (V + 7)/8;
    int start = p*Vc, end = min(V, start + Vc);
    float m = -1e30f, s = 0.f;
    for (int j = start + threadIdx.x; j < end; j += 256) {
        float v = y[(long)b*V + j];
        if (v > m) { s = s*expf(m - v) + 1.f; m = v; }
        else       { s += expf(v - m); }
    }
    __shared__ float ms[256], ss[256];
    ms[threadIdx.x] = m; ss[threadIdx.x] = s;
    __syncthreads();
    for (int st = 128; st; st >>= 1) {
        if (threadIdx.x < st) {
            float m1 = ms[threadIdx.x], s1 = ss[threadIdx.x];
            float m2 = ms[threadIdx.x+st], s2 = ss[threadIdx.x+st];
            float M = fmaxf(m1, m2);
            ms[threadIdx.x] = M;
            ss[threadIdx.x] = s1*expf(m1-M) + s2*expf(m2-M);
        }
        __syncthreads();
    }
    if (threadIdx.x == 0) { part[2*blockIdx.x] = ms[0]; part[2*blockIdx.x+1] = ss[0]; }
}

// ============ fused merge + subtract: each block merges its row's 8 partials =========
__global__ void k_sub2(float* __restrict__ y, const float* __restrict__ part)
{
    const int V = 50257;
    int b = blockIdx.y;
    float M = -1e30f, S = 0.f;
#pragma unroll
    for (int p = 0; p < 8; p++) {
        float m2 = part[2*(b*8+p)], s2 = part[2*(b*8+p)+1];
        float Mn = fmaxf(M, m2);
        S = S*expf(M - Mn) + s2*expf(m2 - Mn);
        M = Mn;
    }
    float lse = M + logf(S);
    int j = blockIdx.x*256 + threadIdx.x;
    if (j < V) y[(long)b*V + j] -= lse;
}

// =====================================================================================
extern "C" void kernel_launch(void* const* d_in, const int* in_sizes, int n_in,
                              void* d_out, int out_size, void* d_ws, size_t ws_size,
                              hipStream_t stream)
{
    const int*   dec_in  = (const int*)  d_in[0];
    const float* attn_h  = (const float*)d_in[1];
    const float* enc     = (const float*)d_in[2];
    // d_in[3] = mask0 (unused: m_w == valid within the window)
    const int*   lengths = (const int*)  d_in[4];
    const float* h0      = (const float*)d_in[5];
    const float* embed   = (const float*)d_in[6];
    const float* w_ih0   = (const float*)d_in[7];
    const float* w_hh0   = (const float*)d_in[8];
    const float* b_ih0   = (const float*)d_in[9];
    const float* b_hh0   = (const float*)d_in[10];
    const float* w_ih1   = (const float*)d_in[11];
    const float* w_hh1   = (const float*)d_in[12];
    const float* b_ih1   = (const float*)d_in[13];
    const float* b_hh1   = (const float*)d_in[14];
    const float* Wp_w    = (const float*)d_in[15];
    const float* Wp_b    = (const float*)d_in[16];
    const float* Vp_w    = (const float*)d_in[17];
    const float* Vp_b    = (const float*)d_in[18];
    const float* Wc_w    = (const float*)d_in[19];
    const float* Wc_b    = (const float*)d_in[20];
    const float* out_w   = (const float*)d_in[21];
    const float* out_b   = (const float*)d_in[22];
    float* y = (float*)d_out;

    // ---- workspace layout, FLOAT units; NO overlaps (verified sizes) ----
    float* ws = (float*)d_ws;
    short* xhi   = (short*)(ws + 0);        // 41,984 fl -> 42,000
    short* xlo   = (short*)(ws + 42000);
    short* h0hi  = (short*)(ws + 84000);    // 65,536 fl -> 65,600
    short* h0lo  = (short*)(ws + 149600);
    short* x1hi  = (short*)(ws + 215200);   // 32,768 fl -> 32,800
    short* x1lo  = (short*)(ws + 248000);
    short* hthi  = (short*)(ws + 280800);
    short* htlo  = (short*)(ws + 313600);
    short* catbf = (short*)(ws + 346400);   // 65,536 fl -> 65,600
    short* habf  = (short*)(ws + 412000);   // 32,768 fl -> 32,800
    float* ht    = ws + 444800;             // 64,000
    float* PgiL0 = ws + 508800;             // 2*5*96000 = 960,000
    float* PghL0 = ws + 1468800;            // 2*2*96000 = 384,000
    float* PgiL1 = ws + 1852800;            // 2*4*96000 = 768,000
    float* PghL1 = ws + 2620800;            // 384,000
    float* Pwp   = ws + 3004800;            // 8*64,000 = 512,000
    float* part  = ws + 3516800;            // 1,024

    dim3 B256(256);

    // 1. prep
    k_prep<<<dim3((64*1312 + 4*64*512 + 1536 + 1536 + 3072 + 255)/256), B256, 0, stream>>>(
        dec_in, attn_h, embed, h0, xhi, xlo, h0hi, h0lo, x1hi, x1lo, hthi, htlo, habf, catbf);

    // 2. all GEMMs independent of x1 (L0 ih + L0 hh + L1 hh)
    k_gru_mm0<<<dim3(24, 5, 6), B256, 0, stream>>>(
        xhi, xlo, h0hi, h0lo, w_ih0, w_hh0, w_hh1, PgiL0, PghL0, PghL1);

    // 3. gates L0 -> x1
    k_gates<0><<<dim3(125, 2), B256, 0, stream>>>(PgiL0, PghL0, h0, b_ih0, b_hh0, x1hi, x1lo, ht, 5, 2);

    // 4. L1 ih GEMM
    k_gru_ih1<<<dim3(24, 4, 2), B256, 0, stream>>>(x1hi, x1lo, w_ih1, PgiL1);

    // 5. gates L1 -> ht
    k_gates<1><<<dim3(125, 2), B256, 0, stream>>>(PgiL1, PghL1, h0, b_ih1, b_hh1, hthi, htlo, ht, 4, 2);

    // 6. Wp GEMM (split-precision)
    k_nn_split4<<<dim3(16, 8), B256, 0, stream>>>(hthi, htlo, Wp_w, Pwp, 1000, 1024, 1000, 4);

    // 7. attention (+pt) -> catbf
    k_attn<<<dim3(64), B256, 0, stream>>>(enc, ht, Pwp, Wp_b, Vp_w, Vp_b, lengths, catbf);

    // 8. Wc GEMM full-K with fused bias+tanh -> habf
    k_wc_full<<<dim3(16), B256, 0, stream>>>(catbf, Wc_w, Wc_b, habf);

    // 9. output projection
    k_out_mm<<<dim3(786), B256, 0, stream>>>(habf, out_w, out_b, y);

    // 10. log_softmax partials
    k_lse_part<<<dim3(512), B256, 0, stream>>>(y, part);

    // 11. merge + subtract
    k_sub2<<<dim3(197, 64), B256, 0, stream>>>(y, part);
}